// Round 2
// baseline (26762.076 us; speedup 1.0000x reference)
//
#include <hip/hip_runtime.h>

typedef __attribute__((ext_vector_type(8))) short short8;
typedef __attribute__((ext_vector_type(4))) short short4v;
typedef __attribute__((ext_vector_type(4))) float float4v;

#define DEV static __device__ __forceinline__

DEV unsigned short f2bf(float f) {
  unsigned u = __float_as_uint(f);
  u += 0x7fffu + ((u >> 16) & 1u);
  return (unsigned short)(u >> 16);
}
DEV float bf2f(unsigned short h) { return __uint_as_float(((unsigned)h) << 16); }
DEV float sigm(float x) { return 1.f / (1.f + __expf(-x)); }

// problem sizes
#define B_    64
#define T_    1024
#define DIN_  512
#define H_    2048
#define DOUT_ 512
#define NZ    8192   // 4*H
#define NCOL  8704   // 4*H + DOUT (y columns appended)
#define KU    2560   // DIN + H

// d_out element offsets: c_f[64][2048], h_f[64][2048], y_f[64][512], ys[64][1024][512]
#define OUT_HF 131072
#define OUT_YF 262144
#define OUT_YS 294912

// workspace layout (bytes). all offsets 16B-aligned.
#define OFF_WCOMBT 0ull
#define SZ_WCOMBT  (8704ull * 2560 * 2)            // 44,564,480
#define OFF_XALL   (OFF_WCOMBT + SZ_WCOMBT)
#define SZ_XALL    (1024ull * 64 * 512 * 2)        // 67,108,864
#define OFF_WIT    (OFF_XALL + SZ_XALL)
#define SZ_WIT     (8192ull * 1024 * 2)            // 16,777,216
#define OFF_WOBF   (OFF_WIT + SZ_WIT)
#define SZ_WOBF    (2048ull * 512 * 2)             //  2,097,152
#define OFF_D0     (OFF_WOBF + SZ_WOBF)
#define SZ_D0      (64ull * 8192 * 4)              //  2,097,152
#define OFF_BPRIME (OFF_D0 + SZ_D0)
#define SZ_BPRIME  (8704ull * 4)                   //     34,816
#define OFF_HBUF   (OFF_BPRIME + SZ_BPRIME)
#define SZ_HBUF    (2ull * 64 * 2048 * 2)          //    524,288 (now unused)
#define OFF_YTMP   (OFF_HBUF + SZ_HBUF)
#define SZ_YTMP    (64ull * 512 * 4)               //    131,072
#define OFF_BAR    (OFF_YTMP + SZ_YTMP)
#define SZ_BAR     (2ull << 20)
#define TOTAL_WS   (OFF_BAR + SZ_BAR)              // ~135.4 MB (unchanged)

// Barrier pages live at the start of the dead WiT region. Page 0 = per-XCD
// leader-election counters; page (t+1) per step t:
//   [g*32]      arrive-L1 counter, g = bz>>5 (8 groups x 32 blocks)
//   [256]       arrive-L2 counter (8 groups)
//   [512+x*32]  per-XCD "L2 invalidated" flag (only used on window-wrap steps)
#define BAR_BYTES (1025ull * 4096)

// 55-slot rolling h window, carved from the rest of WiT + WoBf (dead after
// prep). Slot s holds h_t for t = s mod 55; addresses within a window are
// never reused, so NORMAL CACHED reads can't hit stale L2 lines. One
// buffer_inv per XCD per 55 steps (at window wrap) purges last-window copies.
#define HW_W   55
#define HSLOT  (B_ * H_)                            // 131072 shorts = 256 KiB
#define OFF_HWIN (OFF_WIT + BAR_BYTES)
// OFF_HWIN + 55*262144 = OFF_WIT + 18,616,320 <= OFF_WIT + 18,874,368 (WoBf end)

// LDS layout (dynamic, 163,840 B exactly)
#define LDS_B0 0
#define LDS_B1 65536
#define LDS_X0 131072
#define LDS_X1 147456

// ---------------------------------------------------------------------------
// Prep kernels (unchanged; correctness-verified)
// ---------------------------------------------------------------------------

__global__ void k_transpose_wi(const float* __restrict__ Wi, unsigned short* __restrict__ WiT) {
  __shared__ float tile[32][33];
  const int n0 = blockIdx.x * 32, k0 = blockIdx.y * 32;
  const int tx = threadIdx.x, ty = threadIdx.y; // 32 x 8
#pragma unroll
  for (int i = 0; i < 4; ++i) {
    int kk = ty + i * 8;
    tile[kk][tx] = Wi[(size_t)(k0 + kk) * NZ + n0 + tx];
  }
  __syncthreads();
#pragma unroll
  for (int i = 0; i < 4; ++i) {
    int nn = ty + i * 8;
    WiT[(size_t)(n0 + nn) * 1024 + k0 + tx] = f2bf(tile[tx][nn]);
  }
}

__global__ void k_cvt_wo(const float* __restrict__ Wo, unsigned short* __restrict__ WoBf) {
  size_t i = (size_t)blockIdx.x * 256 + threadIdx.x;
  if (i < 2048ull * 512) WoBf[i] = f2bf(Wo[i]);
}

__global__ void k_wcomb_x(const unsigned short* __restrict__ WiT, unsigned short* __restrict__ WcombT) {
  size_t i = (size_t)blockIdx.x * 256 + threadIdx.x;
  if (i < 524288ull) {
    size_t n = i >> 6, kk = (i & 63) * 8;
    *(short8*)(WcombT + n * KU + kk) = *(const short8*)(WiT + n * 1024 + kk);
  } else if (i < 557056ull) {
    size_t j = i - 524288ull;
    size_t n = 8192 + (j >> 6), kk = (j & 63) * 8;
    short8 z = {0, 0, 0, 0, 0, 0, 0, 0};
    *(short8*)(WcombT + n * KU + kk) = z;
  }
}

__global__ __launch_bounds__(256) void k_wcomb_h(const unsigned short* __restrict__ WoBf,
                                                 const unsigned short* __restrict__ WiT,
                                                 const float* __restrict__ Wh,
                                                 unsigned short* __restrict__ WcombT) {
  const int tid = threadIdx.x;
  const int wave = tid >> 6, lane = tid & 63;
  const int l15 = lane & 15, quad = lane >> 4;
  const int n0 = blockIdx.x * 64;   // 128
  const int km0 = blockIdx.y * 64;  // 32

  const unsigned short* arow = WoBf + (size_t)(km0 + wave * 16 + l15) * 512 + quad * 8;
  const unsigned short* brow0 = WiT + (size_t)(n0 + 0 * 16 + l15) * 1024 + 512 + quad * 8;
  const unsigned short* brow1 = WiT + (size_t)(n0 + 1 * 16 + l15) * 1024 + 512 + quad * 8;
  const unsigned short* brow2 = WiT + (size_t)(n0 + 2 * 16 + l15) * 1024 + 512 + quad * 8;
  const unsigned short* brow3 = WiT + (size_t)(n0 + 3 * 16 + l15) * 1024 + 512 + quad * 8;

  float4v acc0 = {0.f,0.f,0.f,0.f}, acc1 = {0.f,0.f,0.f,0.f}, acc2 = {0.f,0.f,0.f,0.f}, acc3 = {0.f,0.f,0.f,0.f};
#pragma unroll 4
  for (int kk = 0; kk < 16; ++kk) {
    short8 a = *(const short8*)(arow + kk * 32);
    short8 b0 = *(const short8*)(brow0 + kk * 32);
    short8 b1 = *(const short8*)(brow1 + kk * 32);
    short8 b2 = *(const short8*)(brow2 + kk * 32);
    short8 b3 = *(const short8*)(brow3 + kk * 32);
    acc0 = __builtin_amdgcn_mfma_f32_16x16x32_bf16(a, b0, acc0, 0, 0, 0);
    acc1 = __builtin_amdgcn_mfma_f32_16x16x32_bf16(a, b1, acc1, 0, 0, 0);
    acc2 = __builtin_amdgcn_mfma_f32_16x16x32_bf16(a, b2, acc2, 0, 0, 0);
    acc3 = __builtin_amdgcn_mfma_f32_16x16x32_bf16(a, b3, acc3, 0, 0, 0);
  }
#pragma unroll
  for (int tau = 0; tau < 4; ++tau) {
    float4v acc = tau == 0 ? acc0 : (tau == 1 ? acc1 : (tau == 2 ? acc2 : acc3));
    const int n = n0 + tau * 16 + l15;
#pragma unroll
    for (int r = 0; r < 4; ++r) {
      const int km = km0 + wave * 16 + quad * 4 + r;
      float v = acc[r] + Wh[(size_t)km * NZ + n];
      WcombT[(size_t)n * KU + 512 + km] = f2bf(v);
    }
  }
}

__global__ void k_wcomb_y(const float* __restrict__ Wo, unsigned short* __restrict__ WcombT) {
  size_t i = (size_t)blockIdx.x * 256 + threadIdx.x;
  if (i >= 512ull * 2048) return;
  size_t ny = i / 2048, km = i % 2048;
  WcombT[(size_t)(8192 + ny) * KU + 512 + km] = f2bf(Wo[km * 512 + ny]);
}

__global__ void k_bias(const float* __restrict__ b, const float* __restrict__ bo,
                       const float* __restrict__ Wi, float* __restrict__ bprime) {
  int n = blockIdx.x * 256 + threadIdx.x;
  if (n >= NCOL) return;
  if (n < NZ) {
    float a = b[n];
    for (int m = 0; m < 512; ++m) a += bo[m] * Wi[(size_t)(512 + m) * NZ + n];
    bprime[n] = a;
  } else {
    bprime[n] = bo[n - NZ];
  }
}

__global__ void k_ytmp(const float* __restrict__ y0, const float* __restrict__ h0,
                       const float* __restrict__ Wo, const float* __restrict__ bo,
                       float* __restrict__ ytmp) {
  int idx = blockIdx.x * 256 + threadIdx.x;
  if (idx >= 64 * 512) return;
  int m = idx >> 9, n = idx & 511;
  float a = y0[(size_t)m * 512 + n] - bo[n];
  for (int k = 0; k < 2048; ++k) a -= h0[(size_t)m * 2048 + k] * Wo[(size_t)k * 512 + n];
  ytmp[idx] = a;
}

__global__ void k_d0(const float* __restrict__ ytmp, const float* __restrict__ Wi,
                     float* __restrict__ d0) {
  int n = blockIdx.x * 256 + threadIdx.x;
  int m = blockIdx.y;
  if (n >= NZ) return;
  float a = 0.f;
  for (int k = 0; k < 512; ++k) a += ytmp[(size_t)m * 512 + k] * Wi[(size_t)(512 + k) * NZ + n];
  d0[(size_t)m * NZ + n] = a;
}

__global__ void k_xcvt(const float* __restrict__ x, unsigned short* __restrict__ Xall) {
  int t = blockIdx.x, bb = blockIdx.y, k = threadIdx.x * 4;
  float4v v = *(const float4v*)(x + ((size_t)bb * T_ + t) * DIN_ + k);
  short4v o;
  o.x = (short)f2bf(v.x); o.y = (short)f2bf(v.y); o.z = (short)f2bf(v.z); o.w = (short)f2bf(v.w);
  *(short4v*)(Xall + ((size_t)t * B_ + bb) * DIN_ + k) = o;
}

// h0 -> window slot 0 (bf16)
__global__ void k_init(const float* __restrict__ h0, unsigned short* __restrict__ hwin) {
  int i = blockIdx.x * 256 + threadIdx.x;
  if (i >= B_ * H_) return;
  hwin[i] = f2bf(h0[i]);
}

// One-time cache sanitizer, after prep and before persist. The prep kernels
// wrote the reused WiT/WoBf region (bar + h-window) with NORMAL stores; dirty
// L2 lines writing back mid-persist would clobber LLC data, and clean stale
// copies would satisfy window reads. wbl2 pushes dirty lines to LLC, inv drops
// all copies. Every CU issues it -> all 8 XCD L2s are covered.
__global__ void k_flush(void) {
  asm volatile("buffer_wbl2 sc1" ::: "memory");
  asm volatile("s_waitcnt vmcnt(0)" ::: "memory");
  asm volatile("buffer_inv sc1" ::: "memory");
  asm volatile("s_waitcnt vmcnt(0)" ::: "memory");
}

__global__ void k_sentinel(float* out) { out[0] = 1.2345e9f; }

// ---------------------------------------------------------------------------
// h publication: write-through-to-LLC store (sc0 sc1). Leaves no dirty L2
// lines (inv-safe) and is globally visible once vmcnt retires.
// ---------------------------------------------------------------------------
DEV void st_bf16_llc(unsigned short* p, unsigned short v) {
  unsigned vv = v;
  asm volatile("global_store_short %0, %1, off sc0 sc1" :: "v"(p), "v"(vv) : "memory");
}

// ---------------------------------------------------------------------------
// Grid barrier. Normal steps: arrive (relaxed agent atomics, 2-level) + all
// blocks poll the arrive-L2 counter directly — no leader, no flag, no cache
// maintenance. Window-wrap steps (every 55th): per-XCD leader additionally
// issues ONE buffer_inv sc1 (purges last-window h copies) and publishes a
// per-XCD flag that members poll.
// ---------------------------------------------------------------------------
DEV void grid_barrier(int* bar, int t, int tid, int bz, int is_leader,
                      unsigned xcc, int do_inv) {
  asm volatile("s_waitcnt vmcnt(0)" ::: "memory"); // h stores LLC-acked
  __syncthreads();
  if (tid == 0) {
    int* page = bar + (size_t)(t + 1) * 1024;
    int* l1 = page + (bz >> 5) * 32;
    int* l2 = page + 256;
    if (__hip_atomic_fetch_add(l1, 1, __ATOMIC_RELAXED, __HIP_MEMORY_SCOPE_AGENT) == 31)
      __hip_atomic_fetch_add(l2, 1, __ATOMIC_RELAXED, __HIP_MEMORY_SCOPE_AGENT);
    if (do_inv) {
      int* flg = page + 512 + (int)xcc * 32;
      if (is_leader) {
        while (__hip_atomic_load(l2, __ATOMIC_RELAXED, __HIP_MEMORY_SCOPE_AGENT) != 8)
          __builtin_amdgcn_s_sleep(1);
        asm volatile("buffer_inv sc1" ::: "memory");
        asm volatile("s_waitcnt vmcnt(0)" ::: "memory");
        __hip_atomic_store(flg, 1, __ATOMIC_RELAXED, __HIP_MEMORY_SCOPE_AGENT);
      } else {
        while (__hip_atomic_load(flg, __ATOMIC_RELAXED, __HIP_MEMORY_SCOPE_AGENT) == 0)
          __builtin_amdgcn_s_sleep(1);
      }
    } else {
      while (__hip_atomic_load(l2, __ATOMIC_RELAXED, __HIP_MEMORY_SCOPE_AGENT) != 8)
        __builtin_amdgcn_s_sleep(1);
    }
  }
  __syncthreads();
}

// ---------------------------------------------------------------------------
// Persistent kernel: 256 blocks x 256 threads, 1 block/CU (160 KiB LDS).
// h state in a 55-slot rolling window: reads are NORMAL CACHED (32 blocks/XCD
// share L2 lines; LLC->L2 traffic 2 MB/step instead of 64 MB), writes are
// sc0 sc1 write-through. c lives in VGPRs all 1024 steps; next-step x
// fragments prefetched into registers before each barrier.
// ---------------------------------------------------------------------------
__global__ __launch_bounds__(256, 1) void lstm_persist(
    const unsigned short* __restrict__ WcombT, const float* __restrict__ bprime,
    const float* __restrict__ d0, const unsigned short* __restrict__ Xall,
    unsigned short* __restrict__ hwin, const float* __restrict__ c0g,
    int* __restrict__ bar, float* __restrict__ out) {
  extern __shared__ __align__(16) char smem[];
  short8* LB0 = (short8*)(smem + LDS_B0);
  short8* LB1 = (short8*)(smem + LDS_B1);
  short8* LX0 = (short8*)(smem + LDS_X0);
  short8* LX1 = (short8*)(smem + LDS_X1);

  const int tid = threadIdx.x;
  const int wave = tid >> 6;
  const int lane = tid & 63;
  const int l15 = lane & 15;
  const int quad = lane >> 4;
  const int bz = blockIdx.x;

  const int jj = bz * 8 + (l15 & 7);
  const int col0 = (l15 < 8 ? 0 : H_) + jj;          // i | f
  const int col1 = (l15 < 8 ? 2 * H_ : 3 * H_) + jj; // g | o
  const int yj0 = bz * 2;
  const int ycol = yj0 + (l15 & 1); // real for l15<2; duplicate otherwise

  const unsigned short* w0 = WcombT + (size_t)col0 * KU + quad * 8;
  const unsigned short* w1 = WcombT + (size_t)col1 * KU + quad * 8;
  const unsigned short* wy = WcombT + (size_t)(NZ + ycol) * KU + 512 + quad * 8;

  // one-time LDS fill: slot (kk,lane) holds the 16B fragment lane reads at kk.
#pragma unroll
  for (int i = 0; i < 16; ++i) {
    int kk = wave * 16 + i;
    LB0[kk * 64 + lane] = *(const short8*)(w0 + 512 + kk * 32);
    LB1[kk * 64 + lane] = *(const short8*)(w1 + 512 + kk * 32);
  }
#pragma unroll
  for (int i = 0; i < 4; ++i) {
    int kk = wave * 4 + i;
    LX0[kk * 64 + lane] = *(const short8*)(w0 + kk * 32);
    LX1[kk * 64 + lane] = *(const short8*)(w1 + kk * 32);
  }
  __syncthreads();

  // one-time per-XCD leader election (real XCC id, m09: 0..7 on MI355X).
  unsigned xcc;
  asm volatile("s_getreg_b32 %0, hwreg(HW_REG_XCC_ID, 0, 4)" : "=s"(xcc));
  int is_leader = 0;
  if (tid == 0)
    is_leader = (__hip_atomic_fetch_add(bar + (int)xcc * 32, 1, __ATOMIC_RELAXED,
                                        __HIP_MEMORY_SCOPE_AGENT) == 0);

  const int m = wave * 16 + l15;           // A rows
  const float bi0 = bprime[col0];
  const float bi1 = bprime[col1];
  const float biy = bprime[NZ + ycol];
  const int j = bz * 8 + l15;              // output h-col (valid if l15<8)

  float c_r[4] = {0.f, 0.f, 0.f, 0.f};

  // x fragments for step 0
  short8 xr[16];
  {
    const unsigned short* xr0 = Xall + ((size_t)m) * DIN_ + quad * 8;
#pragma unroll
    for (int i = 0; i < 16; ++i) xr[i] = *(const short8*)(xr0 + i * 32);
  }

  int slot_r = 0, slot_w = 1, inv_ctr = HW_W;

  for (int t = 0; t < T_; ++t) {
    const unsigned short* hrow =
        hwin + (size_t)slot_r * HSLOT + (size_t)m * H_ + quad * 8;

    float4v acc0 = {0.f, 0.f, 0.f, 0.f}, acc1 = {0.f, 0.f, 0.f, 0.f}, acc2 = {0.f, 0.f, 0.f, 0.f};

#pragma unroll
    for (int kk = 0; kk < 16; ++kk) {
      short8 a = xr[kk];
      short8 b0 = LX0[kk * 64 + lane];
      short8 b1 = LX1[kk * 64 + lane];
      acc0 = __builtin_amdgcn_mfma_f32_16x16x32_bf16(a, b0, acc0, 0, 0, 0);
      acc1 = __builtin_amdgcn_mfma_f32_16x16x32_bf16(a, b1, acc1, 0, 0, 0);
    }
#pragma unroll 8
    for (int kk = 0; kk < 64; ++kk) {
      short8 a = *(const short8*)(hrow + kk * 32);
      short8 b0 = LB0[kk * 64 + lane];
      short8 b1 = LB1[kk * 64 + lane];
      short8 b2 = *(const short8*)(wy + kk * 32);
      acc0 = __builtin_amdgcn_mfma_f32_16x16x32_bf16(a, b0, acc0, 0, 0, 0);
      acc1 = __builtin_amdgcn_mfma_f32_16x16x32_bf16(a, b1, acc1, 0, 0, 0);
      acc2 = __builtin_amdgcn_mfma_f32_16x16x32_bf16(a, b2, acc2, 0, 0, 0);
    }

#pragma unroll
    for (int r = 0; r < 4; ++r) { acc0[r] += bi0; acc1[r] += bi1; }
    if (t == 0) {
#pragma unroll
      for (int r = 0; r < 4; ++r) {
        int mm = wave * 16 + quad * 4 + r;
        acc0[r] += d0[(size_t)mm * NZ + col0];
        acc1[r] += d0[(size_t)mm * NZ + col1];
      }
    }

    // gate pairing: partner lane^8 holds (f,o) for same j
    float fsh[4], osh[4];
#pragma unroll
    for (int r = 0; r < 4; ++r) {
      fsh[r] = __shfl_xor(acc0[r], 8);
      osh[r] = __shfl_xor(acc1[r], 8);
    }
    unsigned short* hn = hwin + (size_t)slot_w * HSLOT;
    if (l15 < 8) {
#pragma unroll
      for (int r = 0; r < 4; ++r) {
        int mm = wave * 16 + quad * 4 + r;
        float cold = (t == 0) ? c0g[(size_t)mm * H_ + j] : c_r[r];
        float cn = sigm(fsh[r]) * cold + sigm(acc0[r]) * tanhf(acc1[r]);
        float hv = sigm(osh[r]) * tanhf(cn);
        c_r[r] = cn;
        st_bf16_llc(hn + (size_t)mm * H_ + j, f2bf(hv)); // write-through to LLC
        if (t == T_ - 1) {
          out[(size_t)mm * H_ + j] = cn;            // c_f
          out[OUT_HF + (size_t)mm * H_ + j] = hv;   // h_f (full fp32)
        }
      }
    }
    // ys[t-1] = h_t @ Wo + bo (A rows = this step's hrow)
    if (t > 0 && l15 < 2) {
#pragma unroll
      for (int r = 0; r < 4; ++r) {
        int mm = wave * 16 + quad * 4 + r;
        out[(size_t)OUT_YS + (size_t)mm * (T_ * DOUT_) + (size_t)(t - 1) * DOUT_ + ycol] = acc2[r] + biy;
      }
    }

    // prefetch next step's x fragments; loads complete under the barrier wait
    {
      int tn = (t + 1 < T_) ? t + 1 : t;
      const unsigned short* xrn = Xall + ((size_t)tn * B_ + m) * DIN_ + quad * 8;
#pragma unroll
      for (int i = 0; i < 16; ++i) xr[i] = *(const short8*)(xrn + i * 32);
    }

    int do_inv = (--inv_ctr == 0);
    if (do_inv) inv_ctr = HW_W;
    grid_barrier(bar, t, tid, bz, is_leader, xcc, do_inv);

    slot_r = slot_w;
    slot_w = (slot_w + 1 == HW_W) ? 0 : slot_w + 1;
  }

  // tail: ys[1023] = h_1024 @ Wo + bo, also y_f. h_1024 is in slot_r (=34).
  {
    const unsigned short* hrow =
        hwin + (size_t)slot_r * HSLOT + (size_t)m * H_ + quad * 8;
    float4v acc2 = {0.f, 0.f, 0.f, 0.f};
#pragma unroll 4
    for (int kk = 0; kk < 64; ++kk) {
      short8 a = *(const short8*)(hrow + kk * 32);
      short8 b2 = *(const short8*)(wy + kk * 32);
      acc2 = __builtin_amdgcn_mfma_f32_16x16x32_bf16(a, b2, acc2, 0, 0, 0);
    }
    if (l15 < 2) {
#pragma unroll
      for (int r = 0; r < 4; ++r) {
        int mm = wave * 16 + quad * 4 + r;
        float yv = acc2[r] + biy;
        out[(size_t)OUT_YS + (size_t)mm * (T_ * DOUT_) + (size_t)(T_ - 1) * DOUT_ + ycol] = yv;
        out[OUT_YF + (size_t)mm * DOUT_ + ycol] = yv;
      }
    }
  }
}

// ---------------------------------------------------------------------------
extern "C" void kernel_launch(void* const* d_in, const int* in_sizes, int n_in,
                              void* d_out, int out_size, void* d_ws, size_t ws_size,
                              hipStream_t stream) {
  (void)in_sizes; (void)n_in; (void)out_size;
  const float* x  = (const float*)d_in[0];
  const float* c0 = (const float*)d_in[1];
  const float* h0 = (const float*)d_in[2];
  const float* y0 = (const float*)d_in[3];
  const float* Wi = (const float*)d_in[4];
  const float* Wh = (const float*)d_in[5];
  const float* b  = (const float*)d_in[6];
  const float* Wo = (const float*)d_in[7];
  const float* bo = (const float*)d_in[8];
  float* out = (float*)d_out;
  char* ws = (char*)d_ws;

  if (ws_size < TOTAL_WS) {
    k_sentinel<<<1, 1, 0, stream>>>(out);
    return;
  }

  unsigned short* WcombT = (unsigned short*)(ws + OFF_WCOMBT);
  unsigned short* Xall   = (unsigned short*)(ws + OFF_XALL);
  unsigned short* WiT    = (unsigned short*)(ws + OFF_WIT);
  unsigned short* WoBf   = (unsigned short*)(ws + OFF_WOBF);
  float*          d0     = (float*)(ws + OFF_D0);
  float*          bprime = (float*)(ws + OFF_BPRIME);
  float*          ytmp   = (float*)(ws + OFF_YTMP);
  int*            bar    = (int*)(ws + OFF_WIT);        // reused WiT (dead)
  unsigned short* hwin   = (unsigned short*)(ws + OFF_HWIN); // reused WiT/WoBf

  static int lds_attr_set = 0;
  if (!lds_attr_set) {
    hipFuncSetAttribute((const void*)lstm_persist,
                        hipFuncAttributeMaxDynamicSharedMemorySize, 163840);
    lds_attr_set = 1;
  }

  k_transpose_wi<<<dim3(256, 32), dim3(32, 8), 0, stream>>>(Wi, WiT);
  k_cvt_wo<<<4096, 256, 0, stream>>>(Wo, WoBf);
  k_wcomb_x<<<2176, 256, 0, stream>>>(WiT, WcombT);
  k_wcomb_h<<<dim3(128, 32), 256, 0, stream>>>(WoBf, WiT, Wh, WcombT);
  k_wcomb_y<<<4096, 256, 0, stream>>>(Wo, WcombT);
  k_bias<<<34, 256, 0, stream>>>(b, bo, Wi, bprime);
  k_ytmp<<<128, 256, 0, stream>>>(y0, h0, Wo, bo, ytmp);
  k_d0<<<dim3(32, 64), 256, 0, stream>>>(ytmp, Wi, d0);
  k_xcvt<<<dim3(1024, 64), 128, 0, stream>>>(x, Xall);
  k_init<<<512, 256, 0, stream>>>(h0, hwin);   // after last WiT reader

  hipMemsetAsync(bar, 0, BAR_BYTES, stream);   // after last WiT reader

  // sanitize all XCD L2s: push prep/memset dirty lines to LLC, drop all copies
  k_flush<<<256, 64, 0, stream>>>();

  lstm_persist<<<256, 256, 163840, stream>>>(WcombT, bprime, d0, Xall, hwin, c0, bar, out);
}

// Round 3
// 18040.437 us; speedup vs baseline: 1.4834x; 1.4834x over previous
//
#include <hip/hip_runtime.h>

typedef __attribute__((ext_vector_type(8))) short short8;
typedef __attribute__((ext_vector_type(4))) short short4v;
typedef __attribute__((ext_vector_type(4))) float float4v;

#define DEV static __device__ __forceinline__

DEV unsigned short f2bf(float f) {
  unsigned u = __float_as_uint(f);
  u += 0x7fffu + ((u >> 16) & 1u);
  return (unsigned short)(u >> 16);
}
DEV float bf2f(unsigned short h) { return __uint_as_float(((unsigned)h) << 16); }
DEV float sigm(float x) { return 1.f / (1.f + __expf(-x)); }
// tanh via exp identity: ~6 inst vs libdevice tanhf (~30). |err| ~1e-7.
DEV float tanh_fast(float x) {
  float e = __expf(2.f * x);
  return 1.f - 2.f / (e + 1.f);
}

// problem sizes
#define B_    64
#define T_    1024
#define DIN_  512
#define H_    2048
#define DOUT_ 512
#define NZ    8192   // 4*H
#define NCOL  8704   // 4*H + DOUT (y columns appended)
#define KU    2560   // DIN + H

// d_out element offsets: c_f[64][2048], h_f[64][2048], y_f[64][512], ys[64][1024][512]
#define OUT_HF 131072
#define OUT_YF 262144
#define OUT_YS 294912

// workspace layout (bytes). all offsets 16B-aligned.
#define OFF_WCOMBT 0ull
#define SZ_WCOMBT  (8704ull * 2560 * 2)            // 44,564,480
#define OFF_XALL   (OFF_WCOMBT + SZ_WCOMBT)
#define SZ_XALL    (1024ull * 64 * 512 * 2)        // 67,108,864
#define OFF_WIT    (OFF_XALL + SZ_XALL)
#define SZ_WIT     (8192ull * 1024 * 2)            // 16,777,216
#define OFF_WOBF   (OFF_WIT + SZ_WIT)
#define SZ_WOBF    (2048ull * 512 * 2)             //  2,097,152
#define OFF_D0     (OFF_WOBF + SZ_WOBF)
#define SZ_D0      (64ull * 8192 * 4)              //  2,097,152
#define OFF_BPRIME (OFF_D0 + SZ_D0)
#define SZ_BPRIME  (8704ull * 4)                   //     34,816
#define OFF_HBUF   (OFF_BPRIME + SZ_BPRIME)
#define SZ_HBUF    (2ull * 64 * 2048 * 2)          //    524,288 (unused)
#define OFF_YTMP   (OFF_HBUF + SZ_HBUF)
#define SZ_YTMP    (64ull * 512 * 4)               //    131,072
#define OFF_BAR    (OFF_YTMP + SZ_YTMP)
#define SZ_BAR     (2ull << 20)
#define TOTAL_WS   (OFF_BAR + SZ_BAR)              // ~135.4 MB (unchanged)

// Barrier pages at the start of the dead WiT region. Page 0:
//   [x*32]  per-XCD leader-election counters (x = hw XCC_ID)
// Page (t+1) per step t (1024 ints):
//   [g*32]      arrive counter, g = bz>>5 (8 groups x 32 blocks)
//   [512+x*32]  per-XCD release flag
#define BAR_BYTES (1025ull * 4096)

// 55-slot rolling h window in dead WiT/WoBf space: fresh addresses within a
// window => cached reads can't be stale; one leader buffer_inv per XCD per
// 55 steps purges last-window copies.
#define HW_W   55
#define HSLOT  (B_ * H_)                            // 131072 shorts = 256 KiB
#define OFF_HWIN (OFF_WIT + BAR_BYTES)

// LDS layout (dynamic, 163,840 B exactly)
#define LDS_B0 0
#define LDS_B1 65536
#define LDS_X0 131072
#define LDS_X1 147456

// ---------------------------------------------------------------------------
// Prep kernels (unchanged; correctness-verified)
// ---------------------------------------------------------------------------

__global__ void k_transpose_wi(const float* __restrict__ Wi, unsigned short* __restrict__ WiT) {
  __shared__ float tile[32][33];
  const int n0 = blockIdx.x * 32, k0 = blockIdx.y * 32;
  const int tx = threadIdx.x, ty = threadIdx.y; // 32 x 8
#pragma unroll
  for (int i = 0; i < 4; ++i) {
    int kk = ty + i * 8;
    tile[kk][tx] = Wi[(size_t)(k0 + kk) * NZ + n0 + tx];
  }
  __syncthreads();
#pragma unroll
  for (int i = 0; i < 4; ++i) {
    int nn = ty + i * 8;
    WiT[(size_t)(n0 + nn) * 1024 + k0 + tx] = f2bf(tile[tx][nn]);
  }
}

__global__ void k_cvt_wo(const float* __restrict__ Wo, unsigned short* __restrict__ WoBf) {
  size_t i = (size_t)blockIdx.x * 256 + threadIdx.x;
  if (i < 2048ull * 512) WoBf[i] = f2bf(Wo[i]);
}

__global__ void k_wcomb_x(const unsigned short* __restrict__ WiT, unsigned short* __restrict__ WcombT) {
  size_t i = (size_t)blockIdx.x * 256 + threadIdx.x;
  if (i < 524288ull) {
    size_t n = i >> 6, kk = (i & 63) * 8;
    *(short8*)(WcombT + n * KU + kk) = *(const short8*)(WiT + n * 1024 + kk);
  } else if (i < 557056ull) {
    size_t j = i - 524288ull;
    size_t n = 8192 + (j >> 6), kk = (j & 63) * 8;
    short8 z = {0, 0, 0, 0, 0, 0, 0, 0};
    *(short8*)(WcombT + n * KU + kk) = z;
  }
}

__global__ __launch_bounds__(256) void k_wcomb_h(const unsigned short* __restrict__ WoBf,
                                                 const unsigned short* __restrict__ WiT,
                                                 const float* __restrict__ Wh,
                                                 unsigned short* __restrict__ WcombT) {
  const int tid = threadIdx.x;
  const int wave = tid >> 6, lane = tid & 63;
  const int l15 = lane & 15, quad = lane >> 4;
  const int n0 = blockIdx.x * 64;   // 128
  const int km0 = blockIdx.y * 64;  // 32

  const unsigned short* arow = WoBf + (size_t)(km0 + wave * 16 + l15) * 512 + quad * 8;
  const unsigned short* brow0 = WiT + (size_t)(n0 + 0 * 16 + l15) * 1024 + 512 + quad * 8;
  const unsigned short* brow1 = WiT + (size_t)(n0 + 1 * 16 + l15) * 1024 + 512 + quad * 8;
  const unsigned short* brow2 = WiT + (size_t)(n0 + 2 * 16 + l15) * 1024 + 512 + quad * 8;
  const unsigned short* brow3 = WiT + (size_t)(n0 + 3 * 16 + l15) * 1024 + 512 + quad * 8;

  float4v acc0 = {0.f,0.f,0.f,0.f}, acc1 = {0.f,0.f,0.f,0.f}, acc2 = {0.f,0.f,0.f,0.f}, acc3 = {0.f,0.f,0.f,0.f};
#pragma unroll 4
  for (int kk = 0; kk < 16; ++kk) {
    short8 a = *(const short8*)(arow + kk * 32);
    short8 b0 = *(const short8*)(brow0 + kk * 32);
    short8 b1 = *(const short8*)(brow1 + kk * 32);
    short8 b2 = *(const short8*)(brow2 + kk * 32);
    short8 b3 = *(const short8*)(brow3 + kk * 32);
    acc0 = __builtin_amdgcn_mfma_f32_16x16x32_bf16(a, b0, acc0, 0, 0, 0);
    acc1 = __builtin_amdgcn_mfma_f32_16x16x32_bf16(a, b1, acc1, 0, 0, 0);
    acc2 = __builtin_amdgcn_mfma_f32_16x16x32_bf16(a, b2, acc2, 0, 0, 0);
    acc3 = __builtin_amdgcn_mfma_f32_16x16x32_bf16(a, b3, acc3, 0, 0, 0);
  }
#pragma unroll
  for (int tau = 0; tau < 4; ++tau) {
    float4v acc = tau == 0 ? acc0 : (tau == 1 ? acc1 : (tau == 2 ? acc2 : acc3));
    const int n = n0 + tau * 16 + l15;
#pragma unroll
    for (int r = 0; r < 4; ++r) {
      const int km = km0 + wave * 16 + quad * 4 + r;
      float v = acc[r] + Wh[(size_t)km * NZ + n];
      WcombT[(size_t)n * KU + 512 + km] = f2bf(v);
    }
  }
}

__global__ void k_wcomb_y(const float* __restrict__ Wo, unsigned short* __restrict__ WcombT) {
  size_t i = (size_t)blockIdx.x * 256 + threadIdx.x;
  if (i >= 512ull * 2048) return;
  size_t ny = i / 2048, km = i % 2048;
  WcombT[(size_t)(8192 + ny) * KU + 512 + km] = f2bf(Wo[km * 512 + ny]);
}

__global__ void k_bias(const float* __restrict__ b, const float* __restrict__ bo,
                       const float* __restrict__ Wi, float* __restrict__ bprime) {
  int n = blockIdx.x * 256 + threadIdx.x;
  if (n >= NCOL) return;
  if (n < NZ) {
    float a = b[n];
    for (int m = 0; m < 512; ++m) a += bo[m] * Wi[(size_t)(512 + m) * NZ + n];
    bprime[n] = a;
  } else {
    bprime[n] = bo[n - NZ];
  }
}

__global__ void k_ytmp(const float* __restrict__ y0, const float* __restrict__ h0,
                       const float* __restrict__ Wo, const float* __restrict__ bo,
                       float* __restrict__ ytmp) {
  int idx = blockIdx.x * 256 + threadIdx.x;
  if (idx >= 64 * 512) return;
  int m = idx >> 9, n = idx & 511;
  float a = y0[(size_t)m * 512 + n] - bo[n];
  for (int k = 0; k < 2048; ++k) a -= h0[(size_t)m * 2048 + k] * Wo[(size_t)k * 512 + n];
  ytmp[idx] = a;
}

__global__ void k_d0(const float* __restrict__ ytmp, const float* __restrict__ Wi,
                     float* __restrict__ d0) {
  int n = blockIdx.x * 256 + threadIdx.x;
  int m = blockIdx.y;
  if (n >= NZ) return;
  float a = 0.f;
  for (int k = 0; k < 512; ++k) a += ytmp[(size_t)m * 512 + k] * Wi[(size_t)(512 + k) * NZ + n];
  d0[(size_t)m * NZ + n] = a;
}

__global__ void k_xcvt(const float* __restrict__ x, unsigned short* __restrict__ Xall) {
  int t = blockIdx.x, bb = blockIdx.y, k = threadIdx.x * 4;
  float4v v = *(const float4v*)(x + ((size_t)bb * T_ + t) * DIN_ + k);
  short4v o;
  o.x = (short)f2bf(v.x); o.y = (short)f2bf(v.y); o.z = (short)f2bf(v.z); o.w = (short)f2bf(v.w);
  *(short4v*)(Xall + ((size_t)t * B_ + bb) * DIN_ + k) = o;
}

// h0 -> window slot 0 (bf16)
__global__ void k_init(const float* __restrict__ h0, unsigned short* __restrict__ hwin) {
  int i = blockIdx.x * 256 + threadIdx.x;
  if (i >= B_ * H_) return;
  hwin[i] = f2bf(h0[i]);
}

// One-time cache sanitizer between prep and persist (reused WiT/WoBf region
// was written with normal stores; push dirty lines to LLC, drop all copies).
__global__ void k_flush(void) {
  asm volatile("buffer_wbl2 sc1" ::: "memory");
  asm volatile("s_waitcnt vmcnt(0)" ::: "memory");
  asm volatile("buffer_inv sc1" ::: "memory");
  asm volatile("s_waitcnt vmcnt(0)" ::: "memory");
}

__global__ void k_sentinel(float* out) { out[0] = 1.2345e9f; }

// write-through-to-LLC store: no dirty L2 line, visible once vmcnt retires
DEV void st_bf16_llc(unsigned short* p, unsigned short v) {
  unsigned vv = v;
  asm volatile("global_store_short %0, %1, off sc0 sc1" :: "v"(p), "v"(vv) : "memory");
}

// ---------------------------------------------------------------------------
// Persistent kernel: 256 blocks x 256 threads, 1 block/CU.
// Step structure (designed to keep SIMDs issuing -> DVFS up, and to hide the
// barrier wait under recurrence-independent work):
//  (A) critical: preload h_t fragments to regs (ar[64]) -> 128 MFMA -> gates
//      -> h store (sc0 sc1)
//  (B) arrive: vmcnt(0) + syncthreads + per-block atomic on its group counter
//  (C) shadow work: y-GEMM (64 MFMA, reuses ar[]) + ys store; next-step x
//      loads + x-GEMM (32 MFMA)
//  (D) release: leader wave hot-polls the 8 group counters, (wrap: buffer_inv)
//      sets per-XCD flag; all other waves hot-poll the flag (no s_sleep,
//      no s_barrier -> waves keep issuing during the wait)
// ---------------------------------------------------------------------------
__global__ __launch_bounds__(256, 1) void lstm_persist(
    const unsigned short* __restrict__ WcombT, const float* __restrict__ bprime,
    const float* __restrict__ d0, const unsigned short* __restrict__ Xall,
    unsigned short* __restrict__ hwin, const float* __restrict__ c0g,
    int* __restrict__ bar, float* __restrict__ out) {
  extern __shared__ __align__(16) char smem[];
  short8* LB0 = (short8*)(smem + LDS_B0);
  short8* LB1 = (short8*)(smem + LDS_B1);
  short8* LX0 = (short8*)(smem + LDS_X0);
  short8* LX1 = (short8*)(smem + LDS_X1);

  const int tid = threadIdx.x;
  const int wave = tid >> 6;
  const int lane = tid & 63;
  const int l15 = lane & 15;
  const int quad = lane >> 4;
  const int bz = blockIdx.x;

  const int jj = bz * 8 + (l15 & 7);
  const int col0 = (l15 < 8 ? 0 : H_) + jj;          // i | f
  const int col1 = (l15 < 8 ? 2 * H_ : 3 * H_) + jj; // g | o
  const int yj0 = bz * 2;
  const int ycol = yj0 + (l15 & 1); // real for l15<2; duplicate otherwise

  const unsigned short* w0 = WcombT + (size_t)col0 * KU + quad * 8;
  const unsigned short* w1 = WcombT + (size_t)col1 * KU + quad * 8;
  const unsigned short* wy = WcombT + (size_t)(NZ + ycol) * KU + 512 + quad * 8;

  // one-time LDS fill: slot (kk,lane) holds the 16B fragment lane reads at kk.
#pragma unroll
  for (int i = 0; i < 16; ++i) {
    int kk = wave * 16 + i;
    LB0[kk * 64 + lane] = *(const short8*)(w0 + 512 + kk * 32);
    LB1[kk * 64 + lane] = *(const short8*)(w1 + 512 + kk * 32);
  }
#pragma unroll
  for (int i = 0; i < 4; ++i) {
    int kk = wave * 4 + i;
    LX0[kk * 64 + lane] = *(const short8*)(w0 + kk * 32);
    LX1[kk * 64 + lane] = *(const short8*)(w1 + kk * 32);
  }
  __syncthreads();

  // per-XCD leader election; `lead` broadcast within wave0 via shfl.
  unsigned xcc;
  asm volatile("s_getreg_b32 %0, hwreg(HW_REG_XCC_ID, 0, 4)" : "=s"(xcc));
  int lead = 0;
  if (wave == 0) {
    int l = 0;
    if (lane == 0)
      l = (__hip_atomic_fetch_add(bar + (int)xcc * 32, 1, __ATOMIC_RELAXED,
                                  __HIP_MEMORY_SCOPE_AGENT) == 0);
    lead = __shfl(l, 0);
  }

  const int m = wave * 16 + l15;           // A rows
  const float bi0 = bprime[col0];
  const float bi1 = bprime[col1];
  const float biy = bprime[NZ + ycol];
  const int j = bz * 8 + l15;              // output h-col (valid if l15<8)

  float c_r[4] = {0.f, 0.f, 0.f, 0.f};

  // prime x-part for step 0
  float4v xa0 = {0.f, 0.f, 0.f, 0.f}, xa1 = {0.f, 0.f, 0.f, 0.f};
  {
    const unsigned short* xr0 = Xall + ((size_t)m) * DIN_ + quad * 8;
    short8 xr[16];
#pragma unroll
    for (int i = 0; i < 16; ++i) xr[i] = *(const short8*)(xr0 + i * 32);
#pragma unroll
    for (int kk = 0; kk < 16; ++kk) {
      xa0 = __builtin_amdgcn_mfma_f32_16x16x32_bf16(xr[kk], LX0[kk * 64 + lane], xa0, 0, 0, 0);
      xa1 = __builtin_amdgcn_mfma_f32_16x16x32_bf16(xr[kk], LX1[kk * 64 + lane], xa1, 0, 0, 0);
    }
  }

  int slot_r = 0, slot_w = 1, inv_ctr = HW_W;

  for (int t = 0; t < T_; ++t) {
    const unsigned short* hrow =
        hwin + (size_t)slot_r * HSLOT + (size_t)m * H_ + quad * 8;

    // ---- (A) critical path: h-dependent GEMM + gates + h store ----
    short8 ar[64];
#pragma unroll
    for (int kk = 0; kk < 64; ++kk) ar[kk] = *(const short8*)(hrow + kk * 32);

    float4v acc0 = xa0, acc1 = xa1;
#pragma unroll
    for (int kk = 0; kk < 64; ++kk) {
      acc0 = __builtin_amdgcn_mfma_f32_16x16x32_bf16(ar[kk], LB0[kk * 64 + lane], acc0, 0, 0, 0);
      acc1 = __builtin_amdgcn_mfma_f32_16x16x32_bf16(ar[kk], LB1[kk * 64 + lane], acc1, 0, 0, 0);
    }

#pragma unroll
    for (int r = 0; r < 4; ++r) { acc0[r] += bi0; acc1[r] += bi1; }
    if (t == 0) {
#pragma unroll
      for (int r = 0; r < 4; ++r) {
        int mm = wave * 16 + quad * 4 + r;
        acc0[r] += d0[(size_t)mm * NZ + col0];
        acc1[r] += d0[(size_t)mm * NZ + col1];
      }
    }

    // gate pairing: partner lane^8 holds (f,o) for same j
    float fsh[4], osh[4];
#pragma unroll
    for (int r = 0; r < 4; ++r) {
      fsh[r] = __shfl_xor(acc0[r], 8);
      osh[r] = __shfl_xor(acc1[r], 8);
    }
    unsigned short* hn = hwin + (size_t)slot_w * HSLOT;
    if (l15 < 8) {
#pragma unroll
      for (int r = 0; r < 4; ++r) {
        int mm = wave * 16 + quad * 4 + r;
        float cold = (t == 0) ? c0g[(size_t)mm * H_ + j] : c_r[r];
        float cn = sigm(fsh[r]) * cold + sigm(acc0[r]) * tanh_fast(acc1[r]);
        float hv = sigm(osh[r]) * tanh_fast(cn);
        c_r[r] = cn;
        st_bf16_llc(hn + (size_t)mm * H_ + j, f2bf(hv));
        if (t == T_ - 1) {
          out[(size_t)mm * H_ + j] = cn;            // c_f
          out[OUT_HF + (size_t)mm * H_ + j] = hv;   // h_f
        }
      }
    }

    // ---- (B) arrive ----
    int* page = bar + (size_t)(t + 1) * 1024;
    asm volatile("s_waitcnt vmcnt(0)" ::: "memory"); // h stores LLC-acked
    __syncthreads();
    if (tid == 0)
      __hip_atomic_fetch_add(page + (bz >> 5) * 32, 1, __ATOMIC_RELAXED,
                             __HIP_MEMORY_SCOPE_AGENT);

    // ---- (C) shadow work (recurrence-independent) ----
    {
      // next-step x fragments (latency hidden under y-GEMM below)
      int tn = (t + 1 < T_) ? t + 1 : t;
      const unsigned short* xrn = Xall + ((size_t)tn * B_ + m) * DIN_ + quad * 8;
      short8 xr[16];
#pragma unroll
      for (int i = 0; i < 16; ++i) xr[i] = *(const short8*)(xrn + i * 32);

      // y-GEMM: ys[t-1] = h_t @ Wo + bo ; reuses ar[] (still in regs)
      float4v acc2 = {0.f, 0.f, 0.f, 0.f};
#pragma unroll
      for (int kk = 0; kk < 64; ++kk)
        acc2 = __builtin_amdgcn_mfma_f32_16x16x32_bf16(ar[kk], *(const short8*)(wy + kk * 32), acc2, 0, 0, 0);
      if (t > 0 && l15 < 2) {
#pragma unroll
        for (int r = 0; r < 4; ++r) {
          int mm = wave * 16 + quad * 4 + r;
          out[(size_t)OUT_YS + (size_t)mm * (T_ * DOUT_) + (size_t)(t - 1) * DOUT_ + ycol] = acc2[r] + biy;
        }
      }

      // x-GEMM prime for t+1
      float4v n0 = {0.f, 0.f, 0.f, 0.f}, n1 = {0.f, 0.f, 0.f, 0.f};
#pragma unroll
      for (int kk = 0; kk < 16; ++kk) {
        n0 = __builtin_amdgcn_mfma_f32_16x16x32_bf16(xr[kk], LX0[kk * 64 + lane], n0, 0, 0, 0);
        n1 = __builtin_amdgcn_mfma_f32_16x16x32_bf16(xr[kk], LX1[kk * 64 + lane], n1, 0, 0, 0);
      }
      xa0 = n0; xa1 = n1;
    }

    // ---- (D) release: hot polls, no sleep, no s_barrier ----
    {
      int* flg = page + 512 + (int)xcc * 32;
      int do_inv = (--inv_ctr == 0);
      if (do_inv) inv_ctr = HW_W;
      if (wave == 0 && lead) {
        int v;
        do {
          v = __hip_atomic_load(page + (lane & 7) * 32, __ATOMIC_RELAXED,
                                __HIP_MEMORY_SCOPE_AGENT);
        } while (__any(v != 32));
        if (do_inv && lane == 0) {
          asm volatile("buffer_inv sc1" ::: "memory");
          asm volatile("s_waitcnt vmcnt(0)" ::: "memory");
        }
        if (lane == 0)
          __hip_atomic_store(flg, 1, __ATOMIC_RELAXED, __HIP_MEMORY_SCOPE_AGENT);
      } else {
        while (__hip_atomic_load(flg, __ATOMIC_RELAXED, __HIP_MEMORY_SCOPE_AGENT) == 0) {}
      }
      asm volatile("" ::: "memory"); // no hoisting h loads above the release
    }

    slot_r = slot_w;
    slot_w = (slot_w + 1 == HW_W) ? 0 : slot_w + 1;
  }

  // tail: ys[1023] = h_1024 @ Wo + bo, also y_f (h_1024 = window slot_r)
  {
    const unsigned short* hrow =
        hwin + (size_t)slot_r * HSLOT + (size_t)m * H_ + quad * 8;
    float4v acc2 = {0.f, 0.f, 0.f, 0.f};
#pragma unroll 4
    for (int kk = 0; kk < 64; ++kk) {
      short8 a = *(const short8*)(hrow + kk * 32);
      short8 b2 = *(const short8*)(wy + kk * 32);
      acc2 = __builtin_amdgcn_mfma_f32_16x16x32_bf16(a, b2, acc2, 0, 0, 0);
    }
    if (l15 < 2) {
#pragma unroll
      for (int r = 0; r < 4; ++r) {
        int mm = wave * 16 + quad * 4 + r;
        float yv = acc2[r] + biy;
        out[(size_t)OUT_YS + (size_t)mm * (T_ * DOUT_) + (size_t)(T_ - 1) * DOUT_ + ycol] = yv;
        out[OUT_YF + (size_t)mm * DOUT_ + ycol] = yv;
      }
    }
  }
}

// ---------------------------------------------------------------------------
extern "C" void kernel_launch(void* const* d_in, const int* in_sizes, int n_in,
                              void* d_out, int out_size, void* d_ws, size_t ws_size,
                              hipStream_t stream) {
  (void)in_sizes; (void)n_in; (void)out_size;
  const float* x  = (const float*)d_in[0];
  const float* c0 = (const float*)d_in[1];
  const float* h0 = (const float*)d_in[2];
  const float* y0 = (const float*)d_in[3];
  const float* Wi = (const float*)d_in[4];
  const float* Wh = (const float*)d_in[5];
  const float* b  = (const float*)d_in[6];
  const float* Wo = (const float*)d_in[7];
  const float* bo = (const float*)d_in[8];
  float* out = (float*)d_out;
  char* ws = (char*)d_ws;

  if (ws_size < TOTAL_WS) {
    k_sentinel<<<1, 1, 0, stream>>>(out);
    return;
  }

  unsigned short* WcombT = (unsigned short*)(ws + OFF_WCOMBT);
  unsigned short* Xall   = (unsigned short*)(ws + OFF_XALL);
  unsigned short* WiT    = (unsigned short*)(ws + OFF_WIT);
  unsigned short* WoBf   = (unsigned short*)(ws + OFF_WOBF);
  float*          d0     = (float*)(ws + OFF_D0);
  float*          bprime = (float*)(ws + OFF_BPRIME);
  float*          ytmp   = (float*)(ws + OFF_YTMP);
  int*            bar    = (int*)(ws + OFF_WIT);        // reused WiT (dead)
  unsigned short* hwin   = (unsigned short*)(ws + OFF_HWIN); // reused WiT/WoBf

  static int lds_attr_set = 0;
  if (!lds_attr_set) {
    hipFuncSetAttribute((const void*)lstm_persist,
                        hipFuncAttributeMaxDynamicSharedMemorySize, 163840);
    lds_attr_set = 1;
  }

  k_transpose_wi<<<dim3(256, 32), dim3(32, 8), 0, stream>>>(Wi, WiT);
  k_cvt_wo<<<4096, 256, 0, stream>>>(Wo, WoBf);
  k_wcomb_x<<<2176, 256, 0, stream>>>(WiT, WcombT);
  k_wcomb_h<<<dim3(128, 32), 256, 0, stream>>>(WoBf, WiT, Wh, WcombT);
  k_wcomb_y<<<4096, 256, 0, stream>>>(Wo, WcombT);
  k_bias<<<34, 256, 0, stream>>>(b, bo, Wi, bprime);
  k_ytmp<<<128, 256, 0, stream>>>(y0, h0, Wo, bo, ytmp);
  k_d0<<<dim3(32, 64), 256, 0, stream>>>(ytmp, Wi, d0);
  k_xcvt<<<dim3(1024, 64), 128, 0, stream>>>(x, Xall);
  k_init<<<512, 256, 0, stream>>>(h0, hwin);   // after last WiT reader

  hipMemsetAsync(bar, 0, BAR_BYTES, stream);   // after last WiT reader

  // sanitize all XCD L2s before the persist kernel
  k_flush<<<256, 64, 0, stream>>>();

  lstm_persist<<<256, 256, 163840, stream>>>(WcombT, bprime, d0, Xall, hwin, c0, bar, out);
}